// Round 20
// baseline (5474.873 us; speedup 1.0000x reference)
//
#include <hip/hip_runtime.h>
#include <math.h>

#define NSTEPS 200
#define NT     1024         // 2 panels x 8 waves; panel owns 64 batch rows
#define BRB    128          // rows per block (2 panels x 64)
#define SQDT_F 0.07071067811865475f
#define DT_F   0.005f
#define LOSCL  4096.0f            // 2^12
#define LOINV  2.44140625e-4f     // 2^-12

typedef float  f32x4 __attribute__((ext_vector_type(4)));
typedef short  s16x8 __attribute__((ext_vector_type(8)));
typedef _Float16 h16x8 __attribute__((ext_vector_type(8)));
typedef unsigned short u16;
typedef unsigned short us4 __attribute__((ext_vector_type(4)));

// prepacked weight offsets in u16 units (each 128x128 matrix = 32768 u16 as hi/lo frags)
#define ENC_OFF 0
#define W1_OFF  32768
#define W2_OFF  65536
#define WG0_OFF 98304
#define WG1_OFF 131072
#define DEC_OFF 163840
#define WPK_TOT 196608

// ---- fp16 scaled two-term split: x ~= hi + lo*2^-12, |err| <= ~2^-23 |x| ----
__device__ __forceinline__ u16 f2h(float v) {
    _Float16 h = (_Float16)v;                       // v_cvt_f16_f32, RNE
    return __builtin_bit_cast(u16, h);
}
__device__ __forceinline__ float h2f(u16 u) {
    return (float)__builtin_bit_cast(_Float16, u);
}
__device__ __forceinline__ u16 split_hi(float v) { return f2h(v); }
__device__ __forceinline__ u16 split_lo(float v, u16 hi) {
    return f2h((v - h2f(hi)) * LOSCL);              // v-hi exact in fp32; *2^12 exact
}

// GELU via Abramowitz-Stegun 7.1.26 erf (max abs err 1.5e-7 — passed r14 at
// absmax 0.0078; tanh-GELU's 1e-3 failed r2).
__device__ __forceinline__ float gelu_fast(float x) {
    float ax = fabsf(x) * 0.70710678118654752f;     // |x|/sqrt(2)
    float t  = __builtin_amdgcn_rcpf(fmaf(0.3275911f, ax, 1.0f));
    float p  = fmaf(t, 1.061405429f, -1.453152027f);
    p = fmaf(t, p, 1.421413741f);
    p = fmaf(t, p, -0.284496736f);
    p = fmaf(t, p, 0.254829592f);
    p = p * t;
    float e  = __expf(-ax * ax);
    float er = fmaf(-p, e, 1.0f);
    er = copysignf(er, x);
    return 0.5f * x * (1.0f + er);
}

// MFMA via builtin: compiler models hazards (r6/r7 inline-asm MFMA NaN'd).
__device__ __forceinline__ void mfma16(f32x4& d, s16x8 a, s16x8 b) {
    d = __builtin_amdgcn_mfma_f32_16x16x32_f16(
            __builtin_bit_cast(h16x8, a), __builtin_bit_cast(h16x8, b), d, 0, 0, 0);
}
__device__ __forceinline__ s16x8 ldf(const u16* p) {
    return *reinterpret_cast<const s16x8*>(p);
}

// LDS chunk swizzle (r12/r13-validated layout; all sites agree).
__device__ __forceinline__ int swz(int row) {
    return (row & 7) ^ ((row & 8) >> 2);
}

// ---------------- weight prepack (identical to r11-r14) ----------------
// frag layout: base + ((nt*4 + kc)*2 + term)*512 + lane*8 + i   (u16 units)
// element: B[k = kc*32 + (lane>>4)*8 + i][n = nt*16 + (lane&15)]
// sigma column-deinterleaved: WG0 = sig_w[:,0::2], WG1 = sig_w[:,1::2]
__global__ void prepack(const float* __restrict__ enc_w, const float* __restrict__ mu_w1,
                        const float* __restrict__ mu_w2, const float* __restrict__ sig_w,
                        const float* __restrict__ dec_w, u16* __restrict__ wpk)
{
    int u = blockIdx.x * 256 + threadIdx.x;
    if (u >= WPK_TOT) return;
    int mat  = u >> 15;
    int r    = u & 32767;
    int i    = r & 7;
    int lane = (r >> 3) & 63;
    int term = (r >> 9) & 1;
    int kc   = (r >> 10) & 3;
    int nt   = (r >> 12) & 7;
    int k = kc * 32 + (lane >> 4) * 8 + i;
    int n = nt * 16 + (lane & 15);
    float v;
    switch (mat) {
        case 0:  v = enc_w[k * 128 + n];         break;
        case 1:  v = mu_w1[k * 128 + n];         break;
        case 2:  v = mu_w2[k * 128 + n];         break;
        case 3:  v = sig_w[k * 256 + 2 * n];     break;
        case 4:  v = sig_w[k * 256 + 2 * n + 1]; break;
        default: v = dec_w[k * 128 + n];         break;
    }
    u16 hi = split_hi(v);
    wpk[u] = term ? split_lo(v, hi) : hi;
}

// ---------------- main fused SDE kernel ----------------
// r20 = r18/r19 two-panel structure with the occupancy CEILING pinned:
// amdgpu_waves_per_eu(4,4). r19's launch_bounds(NT,4) only set the MINIMUM
// waves/EU — a floor of 4 is satisfied by a 64-reg/8-wave allocation, so the
// allocator kept spilling for an occupancy the 133KB LDS can't deliver
// (VGPR=64, FETCH 9.8GB). Pinning max=4 gives the 512/4=128-reg budget that
// r14's per-thread code provably fits (124 regs, no spill). r18 proved 16
// waves/CU co-residency (47.5% occupancy). This round asks for both at once.
__global__ __launch_bounds__(NT)
__attribute__((amdgpu_waves_per_eu(4, 4)))
void sde_mfma(
    const float* __restrict__ y, const float* __restrict__ noise,
    const float* __restrict__ enc_b, const float* __restrict__ mu_b1,
    const float* __restrict__ mu_b2, const float* __restrict__ sig_b,
    const float* __restrict__ dec_b, const u16* __restrict__ wpk,
    float* __restrict__ out, int Btot)
{
    __shared__ __align__(16) u16 zbh[2][8192];
    __shared__ __align__(16) u16 zbl[2][8192];
    __shared__ __align__(16) u16 hbh[2][8192];
    __shared__ __align__(16) u16 hbl[2][8192];
    __shared__ float nsb[2][2][128];

    const int tid  = threadIdx.x;
    const int pid  = tid >> 9;                      // panel 0/1
    const int ptid = tid & 511;                     // thread within panel
    const int lane = ptid & 63, wid = ptid >> 6;    // wid 0..7
    const int ln   = lane & 15, lg = lane >> 4;
    const size_t brow = (size_t)blockIdx.x * BRB + (size_t)pid * 64;

    const int n0 = wid * 16 + ln;                   // this thread's single col
    const float b10 = mu_b1[n0];
    const float b20 = mu_b2[n0];
    const float bg0 = sig_b[2 * n0];
    const float bg1 = sig_b[2 * n0 + 1];
    const int swzl = swz(ln);                       // A-read chunk swizzle

    // ---- stage y into zb (fp16 hi/lo, swizzled) ----
    #pragma unroll
    for (int c = 0; c < 4; c++) {
        int q = c * 512 + ptid;               // 0..2047 within panel
        int row = q >> 5, k4 = (q & 31) << 2;
        const float4 v = *reinterpret_cast<const float4*>(y + (brow + row) * 128 + k4);
        int idx = row * 128 + (((k4 >> 3) ^ swz(row)) << 3) + (k4 & 7);
        float vv[4] = {v.x, v.y, v.z, v.w};
        us4 hv, lv;
        #pragma unroll
        for (int e = 0; e < 4; e++) {
            u16 h = split_hi(vv[e]);
            u16 l = split_lo(vv[e], h);
            hv[e] = h; lv[e] = l;
        }
        *reinterpret_cast<us4*>(&zbh[pid][idx]) = hv;
        *reinterpret_cast<us4*>(&zbl[pid][idx]) = lv;
    }
    __syncthreads();

    float zr[4][4];   // z state, fp32, carried across all 200 steps

    // ---- encoder: z0 = gelu(y @ enc_w + enc_b) ----
    {
        const float be0 = enc_b[n0];
        f32x4 a0[4], a1[4];
        #pragma unroll
        for (int mt = 0; mt < 4; mt++) {
            a0[mt] = f32x4{be0, be0, be0, be0};
            a1[mt] = f32x4{0, 0, 0, 0};
        }
        #pragma unroll
        for (int kc = 0; kc < 4; kc++) {
            int fo = (((wid << 2) | kc) << 10) + (lane << 3);
            s16x8 bh = ldf(wpk + ENC_OFF + fo);
            s16x8 bl = ldf(wpk + ENC_OFF + fo + 512);
            #pragma unroll
            for (int mt = 0; mt < 4; mt++) {
                int idx = (mt * 16 + ln) * 128 + ((((kc << 2) | lg) ^ swzl) << 3);
                s16x8 ah = ldf(&zbh[pid][idx]);
                s16x8 al = ldf(&zbl[pid][idx]);
                mfma16(a0[mt], ah, bh);
                mfma16(a1[mt], al, bh);
                mfma16(a1[mt], ah, bl);
            }
        }
        #pragma unroll
        for (int mt = 0; mt < 4; mt++)
            #pragma unroll
            for (int r = 0; r < 4; r++)
                zr[mt][r] = gelu_fast(fmaf(a1[mt][r], LOINV, a0[mt][r]));
    }
    __syncthreads();   // all y-tile reads done

    // write z0 into zb; stage noise for t=0
    #pragma unroll
    for (int mt = 0; mt < 4; mt++)
        #pragma unroll
        for (int r = 0; r < 4; r++) {
            int m = 16 * mt + 4 * lg + r;
            int idx = m * 128 + (((n0 >> 3) ^ swz(m)) << 3) + (n0 & 7);
            u16 h = split_hi(zr[mt][r]);
            zbh[pid][idx] = h;
            zbl[pid][idx] = split_lo(zr[mt][r], h);
        }
    if (ptid < 128) nsb[pid][0][ptid] = noise[brow * 2 + ptid];
    __syncthreads();

    // loop-opaque weight pointer: defeats LICM hoisting weight loads into
    // loop-carried registers (the scratch-spill source in r5-r10).
    const u16* wq = wpk;

    // ---- 200 Euler-Maruyama steps, 2 barriers each ----
    for (int t = 0; t < NSTEPS; t++) {
        asm volatile("" : "+s"(wq));
        {   // prefetch next step's noise into the other buffer
            int tn = (t + 1 < NSTEPS) ? (t + 1) : t;
            if (ptid < 128) nsb[pid][(t + 1) & 1][ptid] = noise[((size_t)tn * Btot + brow) * 2 + ptid];
        }
        // pass 1 — G1: h = gelu(z @ W1 + b1) -> hb  (W1 from L2)
        {
            f32x4 a0[4], a1[4];
            #pragma unroll
            for (int mt = 0; mt < 4; mt++) {
                a0[mt] = f32x4{b10, b10, b10, b10};
                a1[mt] = f32x4{0, 0, 0, 0};
            }
            #pragma unroll
            for (int kc = 0; kc < 4; kc++) {
                int fo = (((wid << 2) | kc) << 10) + (lane << 3);
                s16x8 bh = ldf(wq + W1_OFF + fo);
                s16x8 bl = ldf(wq + W1_OFF + fo + 512);
                #pragma unroll
                for (int mt = 0; mt < 4; mt++) {
                    int idx = (mt * 16 + ln) * 128 + ((((kc << 2) | lg) ^ swzl) << 3);
                    s16x8 ah = ldf(&zbh[pid][idx]);
                    s16x8 al = ldf(&zbl[pid][idx]);
                    mfma16(a0[mt], ah, bh);
                    mfma16(a1[mt], al, bh);
                    mfma16(a1[mt], ah, bl);
                }
            }
            #pragma unroll
            for (int mt = 0; mt < 4; mt++)
                #pragma unroll
                for (int r = 0; r < 4; r++) {
                    float hv = gelu_fast(fmaf(a1[mt][r], LOINV, a0[mt][r]));
                    int m = 16 * mt + 4 * lg + r;
                    int idx = m * 128 + (((n0 >> 3) ^ swz(m)) << 3) + (n0 & 7);
                    u16 h = split_hi(hv);
                    hbh[pid][idx] = h;
                    hbl[pid][idx] = split_lo(hv, h);
                }
        }
        // pass 2 — sigma: zr += g0*dw0 + g1*dw1 (Wg0/Wg1 from L2, one A-sweep;
        // unroll 2 pipelines the B-load latency)
        {
            f32x4 q0h[4], q0l[4], q1h[4], q1l[4];
            #pragma unroll
            for (int mt = 0; mt < 4; mt++) {
                q0h[mt] = f32x4{bg0, bg0, bg0, bg0}; q0l[mt] = f32x4{0, 0, 0, 0};
                q1h[mt] = f32x4{bg1, bg1, bg1, bg1}; q1l[mt] = f32x4{0, 0, 0, 0};
            }
            #pragma unroll 2
            for (int kc = 0; kc < 4; kc++) {
                int fo = (((wid << 2) | kc) << 10) + (lane << 3);
                s16x8 b0h = ldf(wq + WG0_OFF + fo);
                s16x8 b0l = ldf(wq + WG0_OFF + fo + 512);
                s16x8 b1h = ldf(wq + WG1_OFF + fo);
                s16x8 b1l = ldf(wq + WG1_OFF + fo + 512);
                #pragma unroll
                for (int mt = 0; mt < 4; mt++) {
                    int idx = (mt * 16 + ln) * 128 + ((((kc << 2) | lg) ^ swzl) << 3);
                    s16x8 ah = ldf(&zbh[pid][idx]);
                    s16x8 al = ldf(&zbl[pid][idx]);
                    mfma16(q0h[mt], ah, b0h);
                    mfma16(q0l[mt], al, b0h);
                    mfma16(q0l[mt], ah, b0l);
                    mfma16(q1h[mt], ah, b1h);
                    mfma16(q1l[mt], al, b1h);
                    mfma16(q1l[mt], ah, b1l);
                }
            }
            const float* np = nsb[pid][t & 1];
            #pragma unroll
            for (int mt = 0; mt < 4; mt++)
                #pragma unroll
                for (int r = 0; r < 4; r++) {
                    int m = 16 * mt + 4 * lg + r;
                    float dw0 = np[2 * m] * SQDT_F;
                    float dw1 = np[2 * m + 1] * SQDT_F;
                    float gv0 = fmaf(q0l[mt][r], LOINV, q0h[mt][r]);
                    float gv1 = fmaf(q1l[mt][r], LOINV, q1h[mt][r]);
                    zr[mt][r] = fmaf(gv0, dw0, fmaf(gv1, dw1, zr[mt][r]));
                }
        }
        __syncthreads();   // bar1: all zb reads done; hb visible

        // pass 3 — G2: drift = h @ W2 + b2; zr += drift*dt; rewrite zb
        {
            f32x4 a0[4], a1[4];
            #pragma unroll
            for (int mt = 0; mt < 4; mt++) {
                a0[mt] = f32x4{b20, b20, b20, b20};
                a1[mt] = f32x4{0, 0, 0, 0};
            }
            #pragma unroll
            for (int kc = 0; kc < 4; kc++) {
                int fo = (((wid << 2) | kc) << 10) + (lane << 3);
                s16x8 bh = ldf(wq + W2_OFF + fo);
                s16x8 bl = ldf(wq + W2_OFF + fo + 512);
                #pragma unroll
                for (int mt = 0; mt < 4; mt++) {
                    int idx = (mt * 16 + ln) * 128 + ((((kc << 2) | lg) ^ swzl) << 3);
                    s16x8 ah = ldf(&hbh[pid][idx]);
                    s16x8 al = ldf(&hbl[pid][idx]);
                    mfma16(a0[mt], ah, bh);
                    mfma16(a1[mt], al, bh);
                    mfma16(a1[mt], ah, bl);
                }
            }
            #pragma unroll
            for (int mt = 0; mt < 4; mt++)
                #pragma unroll
                for (int r = 0; r < 4; r++) {
                    float drift = fmaf(a1[mt][r], LOINV, a0[mt][r]);
                    float v = fmaf(drift, DT_F, zr[mt][r]);
                    zr[mt][r] = v;
                    int m = 16 * mt + 4 * lg + r;
                    int idx = m * 128 + (((n0 >> 3) ^ swz(m)) << 3) + (n0 & 7);
                    u16 h = split_hi(v);
                    zbh[pid][idx] = h;
                    zbl[pid][idx] = split_lo(v, h);
                }
        }
        __syncthreads();   // bar2: new zb visible
    }

    // ---- decoder: out = z @ dec_w + dec_b ----
    {
        const float bd0 = dec_b[n0];
        f32x4 a0[4], a1[4];
        #pragma unroll
        for (int mt = 0; mt < 4; mt++) {
            a0[mt] = f32x4{bd0, bd0, bd0, bd0};
            a1[mt] = f32x4{0, 0, 0, 0};
        }
        #pragma unroll
        for (int kc = 0; kc < 4; kc++) {
            int fo = (((wid << 2) | kc) << 10) + (lane << 3);
            s16x8 bh = ldf(wpk + DEC_OFF + fo);
            s16x8 bl = ldf(wpk + DEC_OFF + fo + 512);
            #pragma unroll
            for (int mt = 0; mt < 4; mt++) {
                int idx = (mt * 16 + ln) * 128 + ((((kc << 2) | lg) ^ swzl) << 3);
                s16x8 ah = ldf(&zbh[pid][idx]);
                s16x8 al = ldf(&zbl[pid][idx]);
                mfma16(a0[mt], ah, bh);
                mfma16(a1[mt], al, bh);
                mfma16(a1[mt], ah, bl);
            }
        }
        #pragma unroll
        for (int mt = 0; mt < 4; mt++)
            #pragma unroll
            for (int r = 0; r < 4; r++) {
                int m = 16 * mt + 4 * lg + r;
                out[(brow + m) * 128 + n0] = fmaf(a1[mt][r], LOINV, a0[mt][r]);
            }
    }
}

extern "C" void kernel_launch(void* const* d_in, const int* in_sizes, int n_in,
                              void* d_out, int out_size, void* d_ws, size_t ws_size,
                              hipStream_t stream) {
    const float* y     = (const float*)d_in[0];
    const float* noise = (const float*)d_in[1];
    const float* enc_w = (const float*)d_in[2];
    const float* enc_b = (const float*)d_in[3];
    const float* mu_w1 = (const float*)d_in[4];
    const float* mu_b1 = (const float*)d_in[5];
    const float* mu_w2 = (const float*)d_in[6];
    const float* mu_b2 = (const float*)d_in[7];
    const float* sig_w = (const float*)d_in[8];
    const float* sig_b = (const float*)d_in[9];
    const float* dec_w = (const float*)d_in[10];
    const float* dec_b = (const float*)d_in[11];
    float* out = (float*)d_out;
    u16* wpk = (u16*)d_ws;

    const int Btot = in_sizes[0] / 128;     // 32768
    prepack<<<(WPK_TOT + 255) / 256, 256, 0, stream>>>(enc_w, mu_w1, mu_w2, sig_w, dec_w, wpk);
    sde_mfma<<<Btot / BRB, NT, 0, stream>>>(y, noise, enc_b, mu_b1, mu_b2, sig_b, dec_b,
                                            wpk, out, Btot);
}

// Round 21
// 2879.339 us; speedup vs baseline: 1.9014x; 1.9014x over previous
//
#include <hip/hip_runtime.h>
#include <math.h>

#define NSTEPS 200
#define NT     512          // 8 waves; each wave owns 16 output cols
#define BR     64
#define SQDT_F 0.07071067811865475f
#define DT_F   0.005f
#define LOSCL  4096.0f            // 2^12
#define LOINV  2.44140625e-4f     // 2^-12

typedef float  f32x4 __attribute__((ext_vector_type(4)));
typedef short  s16x8 __attribute__((ext_vector_type(8)));
typedef _Float16 h16x8 __attribute__((ext_vector_type(8)));
typedef unsigned short u16;
typedef unsigned short us4 __attribute__((ext_vector_type(4)));

// prepacked weight offsets in u16 units (each 128x128 matrix = 32768 u16 as hi/lo frags)
#define ENC_OFF 0
#define W1_OFF  32768
#define W2_OFF  65536
#define WG0_OFF 98304
#define WG1_OFF 131072
#define DEC_OFF 163840
#define WPK_TOT 196608

// ---- fp16 scaled two-term split: x ~= hi + lo*2^-12, |err| <= ~2^-23 |x| ----
__device__ __forceinline__ u16 f2h(float v) {
    _Float16 h = (_Float16)v;                       // v_cvt_f16_f32, RNE
    return __builtin_bit_cast(u16, h);
}
__device__ __forceinline__ float h2f(u16 u) {
    return (float)__builtin_bit_cast(_Float16, u);
}
__device__ __forceinline__ u16 split_hi(float v) { return f2h(v); }
__device__ __forceinline__ u16 split_lo(float v, u16 hi) {
    return f2h((v - h2f(hi)) * LOSCL);              // v-hi exact in fp32; *2^12 exact
}

// GELU via Abramowitz-Stegun 7.1.26 erf (max abs err 1.5e-7 — below the
// fp16-split noise floor; tanh-GELU's 1e-3 failed r2).
__device__ __forceinline__ float gelu_fast(float x) {
    float ax = fabsf(x) * 0.70710678118654752f;     // |x|/sqrt(2)
    float t  = __builtin_amdgcn_rcpf(fmaf(0.3275911f, ax, 1.0f));
    float p  = fmaf(t, 1.061405429f, -1.453152027f);
    p = fmaf(t, p, 1.421413741f);
    p = fmaf(t, p, -0.284496736f);
    p = fmaf(t, p, 0.254829592f);
    p = p * t;
    float e  = __expf(-ax * ax);
    float er = fmaf(-p, e, 1.0f);
    er = copysignf(er, x);
    return 0.5f * x * (1.0f + er);
}

// MFMA via builtin: compiler models hazards (r6/r7 inline-asm MFMA NaN'd).
__device__ __forceinline__ void mfma16(f32x4& d, s16x8 a, s16x8 b) {
    d = __builtin_amdgcn_mfma_f32_16x16x32_f16(
            __builtin_bit_cast(h16x8, a), __builtin_bit_cast(h16x8, b), d, 0, 0, 0);
}
__device__ __forceinline__ s16x8 ldf(const u16* p) {
    return *reinterpret_cast<const s16x8*>(p);
}

// LDS chunk swizzle (r12/r13-validated layout; all sites agree).
__device__ __forceinline__ int swz(int row) {
    return (row & 7) ^ ((row & 8) >> 2);
}

// ---------------- weight prepack (identical to r11-r14) ----------------
// frag layout: base + ((nt*4 + kc)*2 + term)*512 + lane*8 + i   (u16 units)
// element: B[k = kc*32 + (lane>>4)*8 + i][n = nt*16 + (lane&15)]
// sigma column-deinterleaved: WG0 = sig_w[:,0::2], WG1 = sig_w[:,1::2]
__global__ void prepack(const float* __restrict__ enc_w, const float* __restrict__ mu_w1,
                        const float* __restrict__ mu_w2, const float* __restrict__ sig_w,
                        const float* __restrict__ dec_w, u16* __restrict__ wpk)
{
    int u = blockIdx.x * 256 + threadIdx.x;
    if (u >= WPK_TOT) return;
    int mat  = u >> 15;
    int r    = u & 32767;
    int i    = r & 7;
    int lane = (r >> 3) & 63;
    int term = (r >> 9) & 1;
    int kc   = (r >> 10) & 3;
    int nt   = (r >> 12) & 7;
    int k = kc * 32 + (lane >> 4) * 8 + i;
    int n = nt * 16 + (lane & 15);
    float v;
    switch (mat) {
        case 0:  v = enc_w[k * 128 + n];         break;
        case 1:  v = mu_w1[k * 128 + n];         break;
        case 2:  v = mu_w2[k * 128 + n];         break;
        case 3:  v = sig_w[k * 256 + 2 * n];     break;
        case 4:  v = sig_w[k * 256 + 2 * n + 1]; break;
        default: v = dec_w[k * 128 + n];         break;
    }
    u16 hi = split_hi(v);
    wpk[u] = term ? split_lo(v, hi) : hi;
}

// ---------------- main fused SDE kernel ----------------
// FINAL (= round-14 best, 2874 us, 5.9x over round-1 fp32 baseline).
// Architecture: 8 waves x 16 cols, 64-row panel; z/h state in LDS as fp16
// hi/lo splits; zr carried in regs across steps; weights stream per-step
// from L2-resident prepacked d_ws. Session-proven invariants:
//  - asm "+s" on wq: blocks LICM from hoisting weight loads into
//    loop-carried regs (the r5-r10 scratch-spill source; 13 GB -> 36 MB)
//  - MFMA builtin, not inline asm (r6/r7: asm MFMA misses hazard nops -> NaN)
//  - 128-reg envelope respected by construction (allocator won't budge)
//  - A&S-erf GELU: cheap and well under threshold (r14)
// Tested-and-rejected: 32x32 MFMA (r15), BR=32 reshape (r16), swapped
// register-chaining (r17, L2-bound), 1024-thread 2-panel occupancy
// (r18-r20, compiler pins 64 VGPR and spills).
__global__ __launch_bounds__(NT) void sde_mfma(
    const float* __restrict__ y, const float* __restrict__ noise,
    const float* __restrict__ enc_b, const float* __restrict__ mu_b1,
    const float* __restrict__ mu_b2, const float* __restrict__ sig_b,
    const float* __restrict__ dec_b, const u16* __restrict__ wpk,
    float* __restrict__ out, int Btot)
{
    __shared__ __align__(16) u16 zbh[8192];
    __shared__ __align__(16) u16 zbl[8192];
    __shared__ __align__(16) u16 hbh[8192];
    __shared__ __align__(16) u16 hbl[8192];
    __shared__ float nsb[2][128];

    const int tid  = threadIdx.x;
    const int lane = tid & 63, wid = tid >> 6;      // wid 0..7
    const int ln   = lane & 15, lg = lane >> 4;
    const size_t brow = (size_t)blockIdx.x * BR;

    const int n0 = wid * 16 + ln;                   // this thread's single col
    const float b10 = mu_b1[n0];
    const float b20 = mu_b2[n0];
    const float bg0 = sig_b[2 * n0];
    const float bg1 = sig_b[2 * n0 + 1];
    const int swzl = swz(ln);                       // A-read chunk swizzle

    // ---- stage y into zb (fp16 hi/lo, swizzled) ----
    #pragma unroll
    for (int c = 0; c < 4; c++) {
        int q = c * NT + tid;                 // 0..2047
        int row = q >> 5, k4 = (q & 31) << 2;
        const float4 v = *reinterpret_cast<const float4*>(y + (brow + row) * 128 + k4);
        int idx = row * 128 + (((k4 >> 3) ^ swz(row)) << 3) + (k4 & 7);
        float vv[4] = {v.x, v.y, v.z, v.w};
        us4 hv, lv;
        #pragma unroll
        for (int e = 0; e < 4; e++) {
            u16 h = split_hi(vv[e]);
            u16 l = split_lo(vv[e], h);
            hv[e] = h; lv[e] = l;
        }
        *reinterpret_cast<us4*>(zbh + idx) = hv;
        *reinterpret_cast<us4*>(zbl + idx) = lv;
    }
    __syncthreads();

    float zr[4][4];   // z state, fp32, carried across all 200 steps

    // ---- encoder: z0 = gelu(y @ enc_w + enc_b) ----
    {
        const float be0 = enc_b[n0];
        f32x4 a0[4], a1[4];
        #pragma unroll
        for (int mt = 0; mt < 4; mt++) {
            a0[mt] = f32x4{be0, be0, be0, be0};
            a1[mt] = f32x4{0, 0, 0, 0};
        }
        #pragma unroll
        for (int kc = 0; kc < 4; kc++) {
            int fo = (((wid << 2) | kc) << 10) + (lane << 3);
            s16x8 bh = ldf(wpk + ENC_OFF + fo);
            s16x8 bl = ldf(wpk + ENC_OFF + fo + 512);
            #pragma unroll
            for (int mt = 0; mt < 4; mt++) {
                int idx = (mt * 16 + ln) * 128 + ((((kc << 2) | lg) ^ swzl) << 3);
                s16x8 ah = ldf(zbh + idx);
                s16x8 al = ldf(zbl + idx);
                mfma16(a0[mt], ah, bh);
                mfma16(a1[mt], al, bh);
                mfma16(a1[mt], ah, bl);
            }
        }
        #pragma unroll
        for (int mt = 0; mt < 4; mt++)
            #pragma unroll
            for (int r = 0; r < 4; r++)
                zr[mt][r] = gelu_fast(fmaf(a1[mt][r], LOINV, a0[mt][r]));
    }
    __syncthreads();   // all y-tile reads done

    // write z0 into zb; stage noise for t=0
    #pragma unroll
    for (int mt = 0; mt < 4; mt++)
        #pragma unroll
        for (int r = 0; r < 4; r++) {
            int m = 16 * mt + 4 * lg + r;
            int idx = m * 128 + (((n0 >> 3) ^ swz(m)) << 3) + (n0 & 7);
            u16 h = split_hi(zr[mt][r]);
            zbh[idx] = h;
            zbl[idx] = split_lo(zr[mt][r], h);
        }
    if (tid < 128) nsb[0][tid] = noise[brow * 2 + tid];
    __syncthreads();

    // loop-opaque weight pointer: defeats LICM hoisting weight loads into
    // loop-carried registers (the scratch-spill source in r5-r10).
    const u16* wq = wpk;

    // ---- 200 Euler-Maruyama steps, 2 barriers each ----
    for (int t = 0; t < NSTEPS; t++) {
        asm volatile("" : "+s"(wq));
        {   // prefetch next step's noise into the other buffer
            int tn = (t + 1 < NSTEPS) ? (t + 1) : t;
            if (tid < 128) nsb[(t + 1) & 1][tid] = noise[((size_t)tn * Btot + brow) * 2 + tid];
        }
        // pass 1 — G1: h = gelu(z @ W1 + b1) -> hb  (W1 from L2)
        {
            f32x4 a0[4], a1[4];
            #pragma unroll
            for (int mt = 0; mt < 4; mt++) {
                a0[mt] = f32x4{b10, b10, b10, b10};
                a1[mt] = f32x4{0, 0, 0, 0};
            }
            #pragma unroll
            for (int kc = 0; kc < 4; kc++) {
                int fo = (((wid << 2) | kc) << 10) + (lane << 3);
                s16x8 bh = ldf(wq + W1_OFF + fo);
                s16x8 bl = ldf(wq + W1_OFF + fo + 512);
                #pragma unroll
                for (int mt = 0; mt < 4; mt++) {
                    int idx = (mt * 16 + ln) * 128 + ((((kc << 2) | lg) ^ swzl) << 3);
                    s16x8 ah = ldf(zbh + idx);
                    s16x8 al = ldf(zbl + idx);
                    mfma16(a0[mt], ah, bh);
                    mfma16(a1[mt], al, bh);
                    mfma16(a1[mt], ah, bl);
                }
            }
            #pragma unroll
            for (int mt = 0; mt < 4; mt++)
                #pragma unroll
                for (int r = 0; r < 4; r++) {
                    float hv = gelu_fast(fmaf(a1[mt][r], LOINV, a0[mt][r]));
                    int m = 16 * mt + 4 * lg + r;
                    int idx = m * 128 + (((n0 >> 3) ^ swz(m)) << 3) + (n0 & 7);
                    u16 h = split_hi(hv);
                    hbh[idx] = h;
                    hbl[idx] = split_lo(hv, h);
                }
        }
        // pass 2 — sigma: zr += g0*dw0 + g1*dw1 (Wg0/Wg1 from L2, one A-sweep;
        // unroll 2 pipelines the B-load latency)
        {
            f32x4 q0h[4], q0l[4], q1h[4], q1l[4];
            #pragma unroll
            for (int mt = 0; mt < 4; mt++) {
                q0h[mt] = f32x4{bg0, bg0, bg0, bg0}; q0l[mt] = f32x4{0, 0, 0, 0};
                q1h[mt] = f32x4{bg1, bg1, bg1, bg1}; q1l[mt] = f32x4{0, 0, 0, 0};
            }
            #pragma unroll 2
            for (int kc = 0; kc < 4; kc++) {
                int fo = (((wid << 2) | kc) << 10) + (lane << 3);
                s16x8 b0h = ldf(wq + WG0_OFF + fo);
                s16x8 b0l = ldf(wq + WG0_OFF + fo + 512);
                s16x8 b1h = ldf(wq + WG1_OFF + fo);
                s16x8 b1l = ldf(wq + WG1_OFF + fo + 512);
                #pragma unroll
                for (int mt = 0; mt < 4; mt++) {
                    int idx = (mt * 16 + ln) * 128 + ((((kc << 2) | lg) ^ swzl) << 3);
                    s16x8 ah = ldf(zbh + idx);
                    s16x8 al = ldf(zbl + idx);
                    mfma16(q0h[mt], ah, b0h);
                    mfma16(q0l[mt], al, b0h);
                    mfma16(q0l[mt], ah, b0l);
                    mfma16(q1h[mt], ah, b1h);
                    mfma16(q1l[mt], al, b1h);
                    mfma16(q1l[mt], ah, b1l);
                }
            }
            const float* np = nsb[t & 1];
            #pragma unroll
            for (int mt = 0; mt < 4; mt++)
                #pragma unroll
                for (int r = 0; r < 4; r++) {
                    int m = 16 * mt + 4 * lg + r;
                    float dw0 = np[2 * m] * SQDT_F;
                    float dw1 = np[2 * m + 1] * SQDT_F;
                    float gv0 = fmaf(q0l[mt][r], LOINV, q0h[mt][r]);
                    float gv1 = fmaf(q1l[mt][r], LOINV, q1h[mt][r]);
                    zr[mt][r] = fmaf(gv0, dw0, fmaf(gv1, dw1, zr[mt][r]));
                }
        }
        __syncthreads();   // bar1: all zb reads done; hb visible

        // pass 3 — G2: drift = h @ W2 + b2; zr += drift*dt; rewrite zb
        {
            f32x4 a0[4], a1[4];
            #pragma unroll
            for (int mt = 0; mt < 4; mt++) {
                a0[mt] = f32x4{b20, b20, b20, b20};
                a1[mt] = f32x4{0, 0, 0, 0};
            }
            #pragma unroll
            for (int kc = 0; kc < 4; kc++) {
                int fo = (((wid << 2) | kc) << 10) + (lane << 3);
                s16x8 bh = ldf(wq + W2_OFF + fo);
                s16x8 bl = ldf(wq + W2_OFF + fo + 512);
                #pragma unroll
                for (int mt = 0; mt < 4; mt++) {
                    int idx = (mt * 16 + ln) * 128 + ((((kc << 2) | lg) ^ swzl) << 3);
                    s16x8 ah = ldf(hbh + idx);
                    s16x8 al = ldf(hbl + idx);
                    mfma16(a0[mt], ah, bh);
                    mfma16(a1[mt], al, bh);
                    mfma16(a1[mt], ah, bl);
                }
            }
            #pragma unroll
            for (int mt = 0; mt < 4; mt++)
                #pragma unroll
                for (int r = 0; r < 4; r++) {
                    float drift = fmaf(a1[mt][r], LOINV, a0[mt][r]);
                    float v = fmaf(drift, DT_F, zr[mt][r]);
                    zr[mt][r] = v;
                    int m = 16 * mt + 4 * lg + r;
                    int idx = m * 128 + (((n0 >> 3) ^ swz(m)) << 3) + (n0 & 7);
                    u16 h = split_hi(v);
                    zbh[idx] = h;
                    zbl[idx] = split_lo(v, h);
                }
        }
        __syncthreads();   // bar2: new zb visible
    }

    // ---- decoder: out = z @ dec_w + dec_b ----
    {
        const float bd0 = dec_b[n0];
        f32x4 a0[4], a1[4];
        #pragma unroll
        for (int mt = 0; mt < 4; mt++) {
            a0[mt] = f32x4{bd0, bd0, bd0, bd0};
            a1[mt] = f32x4{0, 0, 0, 0};
        }
        #pragma unroll
        for (int kc = 0; kc < 4; kc++) {
            int fo = (((wid << 2) | kc) << 10) + (lane << 3);
            s16x8 bh = ldf(wpk + DEC_OFF + fo);
            s16x8 bl = ldf(wpk + DEC_OFF + fo + 512);
            #pragma unroll
            for (int mt = 0; mt < 4; mt++) {
                int idx = (mt * 16 + ln) * 128 + ((((kc << 2) | lg) ^ swzl) << 3);
                s16x8 ah = ldf(zbh + idx);
                s16x8 al = ldf(zbl + idx);
                mfma16(a0[mt], ah, bh);
                mfma16(a1[mt], al, bh);
                mfma16(a1[mt], ah, bl);
            }
        }
        #pragma unroll
        for (int mt = 0; mt < 4; mt++)
            #pragma unroll
            for (int r = 0; r < 4; r++) {
                int m = 16 * mt + 4 * lg + r;
                out[(brow + m) * 128 + n0] = fmaf(a1[mt][r], LOINV, a0[mt][r]);
            }
    }
}

extern "C" void kernel_launch(void* const* d_in, const int* in_sizes, int n_in,
                              void* d_out, int out_size, void* d_ws, size_t ws_size,
                              hipStream_t stream) {
    const float* y     = (const float*)d_in[0];
    const float* noise = (const float*)d_in[1];
    const float* enc_w = (const float*)d_in[2];
    const float* enc_b = (const float*)d_in[3];
    const float* mu_w1 = (const float*)d_in[4];
    const float* mu_b1 = (const float*)d_in[5];
    const float* mu_w2 = (const float*)d_in[6];
    const float* mu_b2 = (const float*)d_in[7];
    const float* sig_w = (const float*)d_in[8];
    const float* sig_b = (const float*)d_in[9];
    const float* dec_w = (const float*)d_in[10];
    const float* dec_b = (const float*)d_in[11];
    float* out = (float*)d_out;
    u16* wpk = (u16*)d_ws;

    const int Btot = in_sizes[0] / 128;     // 32768
    prepack<<<(WPK_TOT + 255) / 256, 256, 0, stream>>>(enc_w, mu_w1, mu_w2, sig_w, dec_w, wpk);
    sde_mfma<<<Btot / BR, NT, 0, stream>>>(y, noise, enc_b, mu_b1, mu_b2, sig_b, dec_b,
                                           wpk, out, Btot);
}

// Round 22
// 2735.988 us; speedup vs baseline: 2.0011x; 1.0524x over previous
//
#include <hip/hip_runtime.h>
#include <math.h>

#define NSTEPS 200
#define NT     512          // 8 waves; wave jt owns output rows j in [16*jt, 16*jt+16)
#define BR     64
#define SQDT_F 0.07071067811865475f
#define DT_F   0.005f
#define LOSCL  4096.0f            // 2^12
#define LOINV  2.44140625e-4f     // 2^-12

typedef float  f32x4 __attribute__((ext_vector_type(4)));
typedef short  s16x8 __attribute__((ext_vector_type(8)));
typedef _Float16 h16x8 __attribute__((ext_vector_type(8)));
typedef unsigned short u16;
typedef unsigned short us4 __attribute__((ext_vector_type(4)));

// prepacked weight offsets in u16 units (each 128x128 matrix = 32768 u16, A^T kappa-frags)
#define ENC_OFF 0
#define W1_OFF  32768
#define W2_OFF  65536
#define WG0_OFF 98304
#define WG1_OFF 131072
#define DEC_OFF 163840
#define WPK_TOT 196608

// state-frag offset in zx/hx (u16 units): [kc][mt][term][512]
#define FO(kc, mt, term) (((((kc) * 4 + (mt)) * 2) + (term)) * 512)

// ---- fp16 scaled two-term split: x ~= hi + lo*2^-12, |err| <= ~2^-23 |x| ----
__device__ __forceinline__ u16 f2h(float v) {
    _Float16 h = (_Float16)v;                       // v_cvt_f16_f32, RNE
    return __builtin_bit_cast(u16, h);
}
__device__ __forceinline__ float h2f(u16 u) {
    return (float)__builtin_bit_cast(_Float16, u);
}
__device__ __forceinline__ u16 split_hi(float v) { return f2h(v); }
__device__ __forceinline__ u16 split_lo(float v, u16 hi) {
    return f2h((v - h2f(hi)) * LOSCL);              // v-hi exact in fp32; *2^12 exact
}

// GELU via Abramowitz-Stegun 7.1.26 erf (max abs err 1.5e-7 — passed r14 at
// absmax 0.0078; tanh-GELU's 1e-3 failed r2).
__device__ __forceinline__ float gelu_fast(float x) {
    float ax = fabsf(x) * 0.70710678118654752f;     // |x|/sqrt(2)
    float t  = __builtin_amdgcn_rcpf(fmaf(0.3275911f, ax, 1.0f));
    float p  = fmaf(t, 1.061405429f, -1.453152027f);
    p = fmaf(t, p, 1.421413741f);
    p = fmaf(t, p, -0.284496736f);
    p = fmaf(t, p, 0.254829592f);
    p = p * t;
    float e  = __expf(-ax * ax);
    float er = fmaf(-p, e, 1.0f);
    er = copysignf(er, x);
    return 0.5f * x * (1.0f + er);
}

// MFMA via builtin: compiler models hazards (r6/r7 inline-asm MFMA NaN'd).
// d = A@B + d; A = weight^T kappa-frags, B = state^T frags (from C-chaining).
__device__ __forceinline__ void mfma16(f32x4& d, s16x8 a, s16x8 b) {
    d = __builtin_amdgcn_mfma_f32_16x16x32_f16(
            __builtin_bit_cast(h16x8, a), __builtin_bit_cast(h16x8, b), d, 0, 0, 0);
}
__device__ __forceinline__ s16x8 ldf(const u16* p) {
    return *reinterpret_cast<const s16x8*>(p);
}

// ---------------- weight prepack (r17-verified kappa-map) ----------------
// Swapped-GEMM k-slot map: slot i of lane l holds
//   k = kc*32 + 16*(i>>2) + 4*(l>>4) + (i&3)
// A-row (output j/n dim) = nt*16 + (l&15). Contraction is invariant because
// both operands use the SAME kappa bijection (B built from C-layout chaining).
// frag addr: base + ((nt*4 + kc)*2 + term)*512 + lane*8 + i.
// sigma column-deinterleaved: WG0 = sig_w[:,0::2], WG1 = sig_w[:,1::2].
__global__ void prepack(const float* __restrict__ enc_w, const float* __restrict__ mu_w1,
                        const float* __restrict__ mu_w2, const float* __restrict__ sig_w,
                        const float* __restrict__ dec_w, u16* __restrict__ wpk)
{
    int u = blockIdx.x * 256 + threadIdx.x;
    if (u >= WPK_TOT) return;
    int mat  = u >> 15;
    int r    = u & 32767;
    int i    = r & 7;
    int lane = (r >> 3) & 63;
    int term = (r >> 9) & 1;
    int kc   = (r >> 10) & 3;
    int nt   = (r >> 12) & 7;
    int k = kc * 32 + 16 * (i >> 2) + 4 * (lane >> 4) + (i & 3);   // kappa map
    int n = nt * 16 + (lane & 15);
    float v;
    switch (mat) {
        case 0:  v = enc_w[k * 128 + n];         break;
        case 1:  v = mu_w1[k * 128 + n];         break;
        case 2:  v = mu_w2[k * 128 + n];         break;
        case 3:  v = sig_w[k * 256 + 2 * n];     break;
        case 4:  v = sig_w[k * 256 + 2 * n + 1]; break;
        default: v = dec_w[k * 128 + n];         break;
    }
    u16 hi = split_hi(v);
    wpk[u] = term ? split_lo(v, hi) : hi;
}

// ---------------- main fused SDE kernel (transposed, frag-exchange) ----------------
// All GEMMs computed transposed (weights = A). Each wave owns 16 output rows
// (j = 16*jt + 4*lg + r) x all 64 batch cols (m = ln + 16*mt). C-layout output
// IS the next GEMM's B-frag under kappa -> state publish = 16 aligned us4
// vector stores/thread/step (vs r14's 64 scalar u16), and ALL B-frag reads
// are contiguous 1KB wave bursts (r17: zero bank conflicts).
// Same MFMA count / weight-L2 traffic / reg shape / barrier count as r14.
__global__ __launch_bounds__(NT) void sde_mfma(
    const float* __restrict__ y, const float* __restrict__ noise,
    const float* __restrict__ enc_b, const float* __restrict__ mu_b1,
    const float* __restrict__ mu_b2, const float* __restrict__ sig_b,
    const float* __restrict__ dec_b, const u16* __restrict__ wpk,
    float* __restrict__ out, int Btot)
{
    __shared__ __align__(16) u16 zx[16384];   // z^T frags [kc][mt][term][512]
    __shared__ __align__(16) u16 hx[16384];   // h^T frags
    __shared__ float bb[4][128];              // b1, b2, bg0, bg1
    __shared__ float nsb[2][128];

    const int tid  = threadIdx.x;
    const int lane = tid & 63, jt = tid >> 6;       // jt 0..7
    const int ln   = lane & 15, lg = lane >> 4;
    const size_t brow = (size_t)blockIdx.x * BR;

    const int jb  = 16 * jt + 4 * lg;               // output rows j = jb + r
    const int pub = FO(jt >> 1, 0, 0) + lane * 8 + 4 * (jt & 1);  // publish base

    // stage biases into LDS (read volatile in-loop; avoids reg pinning, r17)
    if (tid < 128)      bb[0][tid]       = mu_b1[tid];
    else if (tid < 256) bb[1][tid - 128] = mu_b2[tid - 128];
    else if (tid < 384) bb[2][tid - 256] = sig_b[2 * (tid - 256)];
    else                bb[3][tid - 384] = sig_b[2 * (tid - 384) + 1];
    volatile const float* vb = &bb[0][0];

    // ---- stage y into zx as kappa-map B-frags ----
    // element (m, c): frag(kc=c>>5, mt=m>>4); c mod 32 = 16a + 4b + d ->
    // slot i = 4a+d of lane (m&15)+16b.
    #pragma unroll
    for (int cc = 0; cc < 4; cc++) {
        int q = cc * NT + tid;                 // 0..2047
        int m = q >> 5, cq = (q & 31) << 2;
        const float4 v = *reinterpret_cast<const float4*>(y + (brow + m) * 128 + cq);
        int kc = cq >> 5, a = (cq >> 4) & 1, b = (cq >> 2) & 3;
        int ad = FO(kc, m >> 4, 0) + ((m & 15) + 16 * b) * 8 + 4 * a;
        float vv[4] = {v.x, v.y, v.z, v.w};
        us4 hv, lv;
        #pragma unroll
        for (int e = 0; e < 4; e++) {
            u16 h = split_hi(vv[e]);
            hv[e] = h; lv[e] = split_lo(vv[e], h);
        }
        *reinterpret_cast<us4*>(zx + ad)       = hv;
        *reinterpret_cast<us4*>(zx + ad + 512) = lv;
    }
    __syncthreads();

    float zm[4][4];   // z state [mt][r]: element (m = ln+16*mt, c/j = jb+r)

    // ---- encoder: z0^T = gelu(enc^T @ y^T + enc_b) ----
    {
        f32x4 eb;
        #pragma unroll
        for (int r = 0; r < 4; r++) eb[r] = enc_b[jb + r];
        f32x4 a0[4], a1[4];
        #pragma unroll
        for (int mt = 0; mt < 4; mt++) { a0[mt] = eb; a1[mt] = f32x4{0, 0, 0, 0}; }
        #pragma unroll 2
        for (int kc = 0; kc < 4; kc++) {
            const u16* ap = wpk + ENC_OFF + ((jt * 4 + kc) * 2) * 512 + lane * 8;
            s16x8 wh = ldf(ap), wl = ldf(ap + 512);
            #pragma unroll
            for (int mt = 0; mt < 4; mt++) {
                int zo = FO(kc, mt, 0) + lane * 8;
                s16x8 zh_ = ldf(zx + zo), zl_ = ldf(zx + zo + 512);
                mfma16(a0[mt], wh, zh_);
                mfma16(a1[mt], wl, zh_);
                mfma16(a1[mt], wh, zl_);
            }
        }
        #pragma unroll
        for (int mt = 0; mt < 4; mt++)
            #pragma unroll
            for (int r = 0; r < 4; r++)
                zm[mt][r] = gelu_fast(fmaf(a1[mt][r], LOINV, a0[mt][r]));
    }
    __syncthreads();   // y-frag reads done

    // publish z0; stage noise for t=0
    #pragma unroll
    for (int mt = 0; mt < 4; mt++) {
        us4 hv, lv;
        #pragma unroll
        for (int r = 0; r < 4; r++) {
            u16 h = split_hi(zm[mt][r]);
            hv[r] = h; lv[r] = split_lo(zm[mt][r], h);
        }
        int ad = pub + mt * 1024;
        *reinterpret_cast<us4*>(zx + ad)       = hv;
        *reinterpret_cast<us4*>(zx + ad + 512) = lv;
    }
    if (tid < 128) nsb[0][tid] = noise[brow * 2 + tid];
    __syncthreads();

    // loop-opaque weight pointer: defeats LICM hoisting weight loads into
    // loop-carried registers (the r5-r10 scratch-spill source).
    const u16* wq = wpk;

    // ---- 200 Euler-Maruyama steps, 2 barriers each ----
    for (int t = 0; t < NSTEPS; t++) {
        asm volatile("" : "+s"(wq));
        {   // prefetch next step's noise
            int tn = (t + 1 < NSTEPS) ? (t + 1) : t;
            if (tid < 128) nsb[(t + 1) & 1][tid] = noise[((size_t)tn * Btot + brow) * 2 + tid];
        }
        // pass 1 — G1 swapped: h^T = W1^T @ z^T + b1 -> gelu -> publish hx
        {
            f32x4 b1v;
            #pragma unroll
            for (int r = 0; r < 4; r++) b1v[r] = vb[0 * 128 + jb + r];
            f32x4 a0[4], a1[4];
            #pragma unroll
            for (int mt = 0; mt < 4; mt++) { a0[mt] = b1v; a1[mt] = f32x4{0, 0, 0, 0}; }
            #pragma unroll 2
            for (int kc = 0; kc < 4; kc++) {
                const u16* ap = wq + W1_OFF + ((jt * 4 + kc) * 2) * 512 + lane * 8;
                s16x8 wh = ldf(ap), wl = ldf(ap + 512);
                #pragma unroll
                for (int mt = 0; mt < 4; mt++) {
                    int zo = FO(kc, mt, 0) + lane * 8;
                    s16x8 zh_ = ldf(zx + zo), zl_ = ldf(zx + zo + 512);
                    mfma16(a0[mt], wh, zh_);
                    mfma16(a1[mt], wl, zh_);
                    mfma16(a1[mt], wh, zl_);
                }
            }
            #pragma unroll
            for (int mt = 0; mt < 4; mt++) {
                us4 hv, lv;
                #pragma unroll
                for (int r = 0; r < 4; r++) {
                    float h = gelu_fast(fmaf(a1[mt][r], LOINV, a0[mt][r]));
                    u16 hh = split_hi(h);
                    hv[r] = hh; lv[r] = split_lo(h, hh);
                }
                int ad = pub + mt * 1024;
                *reinterpret_cast<us4*>(hx + ad)       = hv;
                *reinterpret_cast<us4*>(hx + ad + 512) = lv;
            }
        }
        // pass 2 — sigma swapped: g0^T,g1^T = Wg^T @ z^T + bg; zm += g*dw
        {
            f32x4 g0v, g1v;
            #pragma unroll
            for (int r = 0; r < 4; r++) {
                g0v[r] = vb[2 * 128 + jb + r];
                g1v[r] = vb[3 * 128 + jb + r];
            }
            f32x4 q0h[4], q0l[4], q1h[4], q1l[4];
            #pragma unroll
            for (int mt = 0; mt < 4; mt++) {
                q0h[mt] = g0v; q0l[mt] = f32x4{0, 0, 0, 0};
                q1h[mt] = g1v; q1l[mt] = f32x4{0, 0, 0, 0};
            }
            #pragma unroll 2
            for (int kc = 0; kc < 4; kc++) {
                const u16* p0 = wq + WG0_OFF + ((jt * 4 + kc) * 2) * 512 + lane * 8;
                const u16* p1 = wq + WG1_OFF + ((jt * 4 + kc) * 2) * 512 + lane * 8;
                s16x8 w0h = ldf(p0), w0l = ldf(p0 + 512);
                s16x8 w1h = ldf(p1), w1l = ldf(p1 + 512);
                #pragma unroll
                for (int mt = 0; mt < 4; mt++) {
                    int zo = FO(kc, mt, 0) + lane * 8;
                    s16x8 zh_ = ldf(zx + zo), zl_ = ldf(zx + zo + 512);
                    mfma16(q0h[mt], w0h, zh_);
                    mfma16(q0l[mt], w0l, zh_);
                    mfma16(q0l[mt], w0h, zl_);
                    mfma16(q1h[mt], w1h, zh_);
                    mfma16(q1l[mt], w1l, zh_);
                    mfma16(q1l[mt], w1h, zl_);
                }
            }
            const float* np = nsb[t & 1];
            #pragma unroll
            for (int mt = 0; mt < 4; mt++) {
                int mrow = ln + 16 * mt;
                float dw0 = np[2 * mrow] * SQDT_F;
                float dw1 = np[2 * mrow + 1] * SQDT_F;
                #pragma unroll
                for (int r = 0; r < 4; r++) {
                    float gv0 = fmaf(q0l[mt][r], LOINV, q0h[mt][r]);
                    float gv1 = fmaf(q1l[mt][r], LOINV, q1h[mt][r]);
                    zm[mt][r] = fmaf(gv0, dw0, fmaf(gv1, dw1, zm[mt][r]));
                }
            }
        }
        __syncthreads();   // bar1: zx reads done; hx visible

        // pass 3 — G2 swapped: drift^T = W2^T @ h^T + b2; zm += drift*dt; publish zx
        {
            f32x4 b2v;
            #pragma unroll
            for (int r = 0; r < 4; r++) b2v[r] = vb[1 * 128 + jb + r];
            f32x4 a0[4], a1[4];
            #pragma unroll
            for (int mt = 0; mt < 4; mt++) { a0[mt] = b2v; a1[mt] = f32x4{0, 0, 0, 0}; }
            #pragma unroll 2
            for (int kc = 0; kc < 4; kc++) {
                const u16* ap = wq + W2_OFF + ((jt * 4 + kc) * 2) * 512 + lane * 8;
                s16x8 wh = ldf(ap), wl = ldf(ap + 512);
                #pragma unroll
                for (int mt = 0; mt < 4; mt++) {
                    int ho = FO(kc, mt, 0) + lane * 8;
                    s16x8 hh_ = ldf(hx + ho), hl_ = ldf(hx + ho + 512);
                    mfma16(a0[mt], wh, hh_);
                    mfma16(a1[mt], wl, hh_);
                    mfma16(a1[mt], wh, hl_);
                }
            }
            #pragma unroll
            for (int mt = 0; mt < 4; mt++) {
                us4 hv, lv;
                #pragma unroll
                for (int r = 0; r < 4; r++) {
                    float drift = fmaf(a1[mt][r], LOINV, a0[mt][r]);
                    float v = fmaf(drift, DT_F, zm[mt][r]);
                    zm[mt][r] = v;
                    u16 hh = split_hi(v);
                    hv[r] = hh; lv[r] = split_lo(v, hh);
                }
                int ad = pub + mt * 1024;
                *reinterpret_cast<us4*>(zx + ad)       = hv;
                *reinterpret_cast<us4*>(zx + ad + 512) = lv;
            }
        }
        __syncthreads();   // bar2: new zx visible
    }

    // ---- decoder: out^T = dec^T @ z^T + dec_b ----
    {
        f32x4 dbv;
        #pragma unroll
        for (int r = 0; r < 4; r++) dbv[r] = dec_b[jb + r];
        f32x4 a0[4], a1[4];
        #pragma unroll
        for (int mt = 0; mt < 4; mt++) { a0[mt] = dbv; a1[mt] = f32x4{0, 0, 0, 0}; }
        #pragma unroll 2
        for (int kc = 0; kc < 4; kc++) {
            const u16* ap = wpk + DEC_OFF + ((jt * 4 + kc) * 2) * 512 + lane * 8;
            s16x8 wh = ldf(ap), wl = ldf(ap + 512);
            #pragma unroll
            for (int mt = 0; mt < 4; mt++) {
                int zo = FO(kc, mt, 0) + lane * 8;
                s16x8 zh_ = ldf(zx + zo), zl_ = ldf(zx + zo + 512);
                mfma16(a0[mt], wh, zh_);
                mfma16(a1[mt], wl, zh_);
                mfma16(a1[mt], wh, zl_);
            }
        }
        #pragma unroll
        for (int mt = 0; mt < 4; mt++) {
            f32x4 o;
            #pragma unroll
            for (int r = 0; r < 4; r++) o[r] = fmaf(a1[mt][r], LOINV, a0[mt][r]);
            *reinterpret_cast<f32x4*>(out + (brow + ln + 16 * mt) * 128 + jb) = o;
        }
    }
}

extern "C" void kernel_launch(void* const* d_in, const int* in_sizes, int n_in,
                              void* d_out, int out_size, void* d_ws, size_t ws_size,
                              hipStream_t stream) {
    const float* y     = (const float*)d_in[0];
    const float* noise = (const float*)d_in[1];
    const float* enc_w = (const float*)d_in[2];
    const float* enc_b = (const float*)d_in[3];
    const float* mu_w1 = (const float*)d_in[4];
    const float* mu_b1 = (const float*)d_in[5];
    const float* mu_w2 = (const float*)d_in[6];
    const float* mu_b2 = (const float*)d_in[7];
    const float* sig_w = (const float*)d_in[8];
    const float* sig_b = (const float*)d_in[9];
    const float* dec_w = (const float*)d_in[10];
    const float* dec_b = (const float*)d_in[11];
    float* out = (float*)d_out;
    u16* wpk = (u16*)d_ws;

    const int Btot = in_sizes[0] / 128;     // 32768
    prepack<<<(WPK_TOT + 255) / 256, 256, 0, stream>>>(enc_w, mu_w1, mu_w2, sig_w, dec_w, wpk);
    sde_mfma<<<Btot / BR, NT, 0, stream>>>(y, noise, enc_b, mu_b1, mu_b2, sig_b, dec_b,
                                           wpk, out, Btot);
}